// Round 2
// baseline (1369.457 us; speedup 1.0000x reference)
//
#include <hip/hip_runtime.h>
#include <hip/hip_bf16.h>

// Problem constants (shapes fixed by setup_inputs)
#define F_IN  500
#define HC    128   // H*C
#define NHEAD 8
#define CDIM  16
#define NCLS  16

static __device__ __forceinline__ float bf(const __hip_bfloat16 v) {
    return __bfloat162float(v);
}

// dual-dtype load: harness may give bf16 or fp32 float tensors; flag decides.
static __device__ __forceinline__ float ldf(const void* p, size_t i, int isbf) {
    return isbf ? __bfloat162float(((const __hip_bfloat16*)p)[i])
                : ((const float*)p)[i];
}

// ordered-uint encoding for float atomicMax
static __device__ __forceinline__ unsigned int enc_f32(float f) {
    unsigned int u = __float_as_uint(f);
    return (u & 0x80000000u) ? ~u : (u | 0x80000000u);
}
static __device__ __forceinline__ float dec_f32(unsigned int u) {
    return __uint_as_float((u & 0x80000000u) ? (u & 0x7FFFFFFFu) : ~u);
}

// ---------------------------------------------------------------- dtype probe
// Examine even-indexed uint16s of x. If buffer is bf16, those are real bf16
// values of N(0,1) data (exponent field ~[110,135] nearly always). If buffer
// is fp32, they are low mantissa bits (uniform junk, ~10% in range).
__global__ void detect_dtype_kernel(const unsigned short* __restrict__ x,
                                    int* __restrict__ flag)
{
    __shared__ int cnt;
    if (threadIdx.x == 0) cnt = 0;
    __syncthreads();
    int ok = 0;
    for (int k = threadIdx.x * 4; k < threadIdx.x * 4 + 4; k++) {
        unsigned short v = x[2 * k];
        int e = (v >> 7) & 0xFF;
        if (e >= 110 && e <= 135) ok++;
    }
    atomicAdd(&cnt, ok);
    __syncthreads();
    if (threadIdx.x == 0) *flag = (cnt > 512) ? 1 : 0;
}

// ---------------------------------------------------------------- zero fill
__global__ void zero_f32(float* __restrict__ p, int n) {
    int i = blockIdx.x * blockDim.x + threadIdx.x;
    if (i < n) p[i] = 0.f;
}

// ---------------------------------------------------------------- GEMM1: h1 = x @ W1   [N,500]x[500,128] -> fp32
#define BM 64
#define BK 10
__global__ __launch_bounds__(256) void gemm1_kernel(
    const void* __restrict__ x, const void* __restrict__ W1,
    float* __restrict__ h1, int N, const int* __restrict__ dflag)
{
    const int isbf = *dflag;
    __shared__ float xs[BK][BM];      // transposed x tile
    __shared__ float wst[BK][HC];
    const int m0 = blockIdx.x * BM;
    const int tid = threadIdx.x;
    const int rb = (tid >> 5) << 3;   // 8 rows per thread
    const int cb = (tid & 31) << 2;   // 4 cols per thread

    float acc[8][4];
#pragma unroll
    for (int i = 0; i < 8; i++)
#pragma unroll
        for (int j = 0; j < 4; j++) acc[i][j] = 0.f;

    for (int k0 = 0; k0 < F_IN; k0 += BK) {
        for (int idx = tid; idx < BM * BK; idx += 256) {
            int r = idx / BK, kk = idx - r * BK;
            int row = m0 + r;
            xs[kk][r] = (row < N) ? ldf(x, (size_t)row * F_IN + k0 + kk, isbf) : 0.f;
        }
        for (int idx = tid; idx < BK * HC; idx += 256) {
            int kk = idx >> 7, c = idx & 127;
            wst[kk][c] = ldf(W1, (size_t)(k0 + kk) * HC + c, isbf);
        }
        __syncthreads();
#pragma unroll
        for (int kk = 0; kk < BK; ++kk) {
            float xv[8], wv[4];
#pragma unroll
            for (int i = 0; i < 8; i++) xv[i] = xs[kk][rb + i];
#pragma unroll
            for (int j = 0; j < 4; j++) wv[j] = wst[kk][cb + j];
#pragma unroll
            for (int i = 0; i < 8; i++)
#pragma unroll
                for (int j = 0; j < 4; j++) acc[i][j] += xv[i] * wv[j];
        }
        __syncthreads();
    }
#pragma unroll
    for (int i = 0; i < 8; i++) {
        int row = m0 + rb + i;
        if (row < N) {
#pragma unroll
            for (int j = 0; j < 4; j++)
                h1[(size_t)row * HC + cb + j] = acc[i][j];
        }
    }
}

// ---------------------------------------------------------------- per-node attention dots for layer 1
// d1[j*N*8 + n*8 + h] = sum_c h1[n,h,c] * a1[j,h,c]
__global__ void dots1_kernel(const float* __restrict__ h1,
                             const void* __restrict__ a1,
                             float* __restrict__ d1, int N,
                             const int* __restrict__ dflag)
{
    const int isbf = *dflag;
    int id = blockIdx.x * blockDim.x + threadIdx.x;
    if (id >= N * NHEAD) return;
    int n = id >> 3, h = id & 7;
    const float* hp = h1 + (size_t)n * HC + h * CDIM;
    float s0 = 0.f, s1 = 0.f, s2 = 0.f;
#pragma unroll
    for (int c = 0; c < CDIM; c++) {
        float v = hp[c];
        s0 += v * ldf(a1, (0 * NHEAD + h) * CDIM + c, isbf);
        s1 += v * ldf(a1, (1 * NHEAD + h) * CDIM + c, isbf);
        s2 += v * ldf(a1, (2 * NHEAD + h) * CDIM + c, isbf);
    }
    d1[id] = s0;
    d1[N * NHEAD + id] = s1;
    d1[2 * N * NHEAD + id] = s2;
}

// ---------------------------------------------------------------- layer1 pass A: logits + segment max
__global__ void attn1_max_kernel(const int* __restrict__ pidx,
                                 const float* __restrict__ d1,
                                 __hip_bfloat16* __restrict__ e1,
                                 unsigned int* __restrict__ m1, int N, int P)
{
    int id = blockIdx.x * blockDim.x + threadIdx.x;
    if (id >= P * NHEAD) return;
    int p = id >> 3, h = id & 7;
    int hd = pidx[p], md = pidx[P + p], tl = pidx[2 * P + p];
    float e = d1[hd * NHEAD + h] + d1[N * NHEAD + md * NHEAD + h] + d1[2 * N * NHEAD + tl * NHEAD + h];
    e = e > 0.f ? e : 0.2f * e;   // leaky relu
    e1[id] = __float2bfloat16(e);
    atomicMax(m1 + hd * NHEAD + h, enc_f32(e));
}

// ---------------------------------------------------------------- layer1 pass B: exp, denom, weighted numerator scatter
__global__ void attn1_agg_kernel(const int* __restrict__ pidx,
                                 const __hip_bfloat16* __restrict__ e1,
                                 const unsigned int* __restrict__ m1,
                                 const float* __restrict__ h1,
                                 float* __restrict__ num1,
                                 float* __restrict__ s1, int N, int P)
{
    int id = blockIdx.x * blockDim.x + threadIdx.x;
    if (id >= P * HC) return;
    int p = id >> 7, j = id & 127, h = j >> 4;
    int hd = pidx[p], tl = pidx[2 * P + p];
    float e = bf(e1[p * NHEAD + h]);
    float m = dec_f32(m1[hd * NHEAD + h]);
    float ex = __expf(e - m);
    float v = h1[(size_t)tl * HC + j];
    atomicAdd(num1 + (size_t)hd * HC + j, ex * v);
    if ((j & 15) == 0) atomicAdd(s1 + hd * NHEAD + h, ex);
}

// ---------------------------------------------------------------- layer1 pass C: normalize + bias + elu (in place into num1)
__global__ void finish1_kernel(float* __restrict__ num1,
                               const float* __restrict__ s1,
                               const void* __restrict__ b1, int N,
                               const int* __restrict__ dflag)
{
    const int isbf = *dflag;
    int id = blockIdx.x * blockDim.x + threadIdx.x;
    if (id >= N * HC) return;
    int n = id >> 7, j = id & 127, h = j >> 4;
    float v = num1[id] / (s1[n * NHEAD + h] + 1e-16f) + ldf(b1, j, isbf);
    num1[id] = v > 0.f ? v : __expf(v) - 1.f;   // elu
}

// ---------------------------------------------------------------- layer2 GEMM + dots: h2 = elu @ W2 ; d2[j,n] = h2[n,:]·a2[j]
__global__ __launch_bounds__(256) void layer2_kernel(
    const float* __restrict__ elu, const void* __restrict__ W2,
    const void* __restrict__ a2,
    float* __restrict__ h2, float* __restrict__ d2, int N,
    const int* __restrict__ dflag)
{
    const int isbf = *dflag;
    __shared__ float rows[16][HC + 1];
    __shared__ float h2s[16][NCLS + 1];
    const int n0 = blockIdx.x * 16;
    const int tid = threadIdx.x;
    for (int idx = tid; idx < 16 * HC; idx += 256) {
        int r = idx >> 7, c = idx & 127;
        rows[r][c] = (n0 + r < N) ? elu[(size_t)(n0 + r) * HC + c] : 0.f;
    }
    __syncthreads();
    int ln = tid >> 4, c = tid & 15;
    float acc = 0.f;
#pragma unroll 8
    for (int j = 0; j < HC; j++) acc += rows[ln][j] * ldf(W2, (size_t)j * NCLS + c, isbf);
    h2s[ln][c] = acc;
    if (n0 + ln < N) h2[(size_t)(n0 + ln) * NCLS + c] = acc;
    __syncthreads();
    if (tid < 48) {
        int l = tid / 3, j = tid - l * 3;
        if (n0 + l < N) {
            float s = 0.f;
#pragma unroll
            for (int cc = 0; cc < NCLS; cc++) s += h2s[l][cc] * ldf(a2, j * NCLS + cc, isbf);
            d2[j * N + n0 + l] = s;
        }
    }
}

// ---------------------------------------------------------------- layer2 pass A
__global__ void attn2_max_kernel(const int* __restrict__ pidx,
                                 const float* __restrict__ d2,
                                 float* __restrict__ e2,
                                 unsigned int* __restrict__ m2, int N, int P)
{
    int p = blockIdx.x * blockDim.x + threadIdx.x;
    if (p >= P) return;
    int hd = pidx[p], md = pidx[P + p], tl = pidx[2 * P + p];
    float e = d2[hd] + d2[N + md] + d2[2 * N + tl];
    e = e > 0.f ? e : 0.2f * e;
    e2[p] = e;
    atomicMax(m2 + hd, enc_f32(e));
}

// ---------------------------------------------------------------- layer2 pass B
__global__ void attn2_agg_kernel(const int* __restrict__ pidx,
                                 const float* __restrict__ e2,
                                 const unsigned int* __restrict__ m2,
                                 const float* __restrict__ h2,
                                 float* __restrict__ num2,
                                 float* __restrict__ s2, int N, int P)
{
    int id = blockIdx.x * blockDim.x + threadIdx.x;
    if (id >= P * NCLS) return;
    int p = id >> 4, c = id & 15;
    int hd = pidx[p], tl = pidx[2 * P + p];
    float ex = __expf(e2[p] - dec_f32(m2[hd]));
    atomicAdd(num2 + (size_t)hd * NCLS + c, ex * h2[(size_t)tl * NCLS + c]);
    if (c == 0) atomicAdd(s2 + hd, ex);
}

// ---------------------------------------------------------------- layer2 pass C: normalize + bias + log_softmax -> out (dtype per flag)
__global__ void finish2_kernel(const float* __restrict__ num2,
                               const float* __restrict__ s2,
                               const void* __restrict__ b2,
                               void* __restrict__ out, int N,
                               const int* __restrict__ dflag)
{
    const int isbf = *dflag;
    int n = blockIdx.x * blockDim.x + threadIdx.x;
    if (n >= N) return;
    float s = s2[n] + 1e-16f;
    float o[NCLS];
    float mx = -3.4e38f;
#pragma unroll
    for (int c = 0; c < NCLS; c++) {
        o[c] = num2[(size_t)n * NCLS + c] / s + ldf(b2, c, isbf);
        mx = fmaxf(mx, o[c]);
    }
    float l = 0.f;
#pragma unroll
    for (int c = 0; c < NCLS; c++) l += __expf(o[c] - mx);
    l = logf(l);
    if (isbf) {
        __hip_bfloat16* ob = (__hip_bfloat16*)out;
#pragma unroll
        for (int c = 0; c < NCLS; c++)
            ob[(size_t)n * NCLS + c] = __float2bfloat16(o[c] - mx - l);
    } else {
        float* of = (float*)out;
#pragma unroll
        for (int c = 0; c < NCLS; c++)
            of[(size_t)n * NCLS + c] = o[c] - mx - l;
    }
}

// ================================================================ launch
extern "C" void kernel_launch(void* const* d_in, const int* in_sizes, int n_in,
                              void* d_out, int out_size, void* d_ws, size_t ws_size,
                              hipStream_t stream)
{
    const void* x  = d_in[0];
    const int*  pi = (const int*)d_in[1];
    const void* W1 = d_in[2];
    const void* a1 = d_in[3];
    const void* b1 = d_in[4];
    const void* W2 = d_in[5];
    const void* a2 = d_in[6];
    const void* b2 = d_in[7];

    const int N = in_sizes[0] / F_IN;   // 100000
    const int P = in_sizes[1] / 3;      // 1000000

    float* ws = (float*)d_ws;
    // fp32 workspace layout (float units). e1 is bf16 (4P float-slots for 8P
    // elems). Layer-2 block aliases the dead e1 region. Peak = 343N + 1 floats
    // (~137.2 MB at N=100000,P=1000000).
    size_t off_h1   = 0;                       // 128N
    size_t off_d1   = (size_t)128 * N;         // 24N
    size_t off_m1   = (size_t)152 * N;         // 8N (uint enc)
    size_t off_s1   = (size_t)160 * N;         // 8N
    size_t off_num1 = (size_t)168 * N;         // 128N
    size_t off_e1   = (size_t)296 * N;         // 4P (bf16 x 8P)
    size_t off_h2   = (size_t)296 * N;         // 16N  (aliases dead e1)
    size_t off_d2   = (size_t)312 * N;         // 3N
    size_t off_m2   = (size_t)315 * N;         // N
    size_t off_s2   = (size_t)316 * N;         // N
    size_t off_num2 = (size_t)317 * N;         // 16N
    size_t off_e2   = (size_t)333 * N;         // P (aliases dead e1 tail)
    size_t off_flag = (size_t)343 * N;         // 1

    float* h1   = ws + off_h1;
    float* d1   = ws + off_d1;
    unsigned int* m1 = (unsigned int*)(ws + off_m1);
    float* s1   = ws + off_s1;
    float* num1 = ws + off_num1;
    __hip_bfloat16* e1 = (__hip_bfloat16*)(ws + off_e1);
    float* h2   = ws + off_h2;
    float* d2   = ws + off_d2;
    unsigned int* m2 = (unsigned int*)(ws + off_m2);
    float* s2   = ws + off_s2;
    float* num2 = ws + off_num2;
    float* e2   = ws + off_e2;
    int*   dflag = (int*)(ws + off_flag);

    const int BLK = 256;
    detect_dtype_kernel<<<1, 256, 0, stream>>>((const unsigned short*)x, dflag);
    // zero layer-1 accumulators: m1,s1,num1 contiguous (152N..296N) = 144N floats
    {
        int cnt = 144 * N;
        zero_f32<<<(cnt + BLK - 1) / BLK, BLK, 0, stream>>>(ws + off_m1, cnt);
    }
    gemm1_kernel<<<(N + BM - 1) / BM, 256, 0, stream>>>(x, W1, h1, N, dflag);
    dots1_kernel<<<(N * NHEAD + BLK - 1) / BLK, BLK, 0, stream>>>(h1, a1, d1, N, dflag);
    attn1_max_kernel<<<(P * NHEAD + BLK - 1) / BLK, BLK, 0, stream>>>(pi, d1, e1, m1, N, P);
    attn1_agg_kernel<<<((size_t)P * HC + BLK - 1) / BLK, BLK, 0, stream>>>(pi, e1, m1, h1, num1, s1, N, P);
    finish1_kernel<<<(N * HC + BLK - 1) / BLK, BLK, 0, stream>>>(num1, s1, b1, N, dflag);
    // zero layer-2 accumulators: m2,s2,num2 contiguous (315N..333N) = 18N floats
    {
        int cnt = 18 * N;
        zero_f32<<<(cnt + BLK - 1) / BLK, BLK, 0, stream>>>(ws + off_m2, cnt);
    }
    layer2_kernel<<<(N + 15) / 16, 256, 0, stream>>>(num1, W2, a2, h2, d2, N, dflag);
    attn2_max_kernel<<<(P + BLK - 1) / BLK, BLK, 0, stream>>>(pi, d2, e2, m2, N, P);
    attn2_agg_kernel<<<(P * NCLS + BLK - 1) / BLK, BLK, 0, stream>>>(pi, e2, m2, h2, num2, s2, N, P);
    finish2_kernel<<<(N + BLK - 1) / BLK, BLK, 0, stream>>>(num2, s2, b2, out_size ? d_out : d_out, N, dflag);
}

// Round 3
// 1063.935 us; speedup vs baseline: 1.2872x; 1.2872x over previous
//
#include <hip/hip_runtime.h>
#include <hip/hip_bf16.h>

// Problem constants (shapes fixed by setup_inputs)
#define F_IN  500
#define HC    128   // H*C
#define NHEAD 8
#define CDIM  16
#define NCLS  16

static __device__ __forceinline__ float bf(const __hip_bfloat16 v) {
    return __bfloat162float(v);
}

// dual-dtype load: harness may give bf16 or fp32 float tensors; flag decides.
static __device__ __forceinline__ float ldf(const void* p, size_t i, int isbf) {
    return isbf ? __bfloat162float(((const __hip_bfloat16*)p)[i])
                : ((const float*)p)[i];
}

// ---------------------------------------------------------------- dtype probe
__global__ void detect_dtype_kernel(const unsigned short* __restrict__ x,
                                    int* __restrict__ flag)
{
    __shared__ int cnt;
    if (threadIdx.x == 0) cnt = 0;
    __syncthreads();
    int ok = 0;
    for (int k = threadIdx.x * 4; k < threadIdx.x * 4 + 4; k++) {
        unsigned short v = x[2 * k];
        int e = (v >> 7) & 0xFF;
        if (e >= 110 && e <= 135) ok++;
    }
    atomicAdd(&cnt, ok);
    __syncthreads();
    if (threadIdx.x == 0) *flag = (cnt > 512) ? 1 : 0;
}

// ---------------------------------------------------------------- zero fill (ints)
__global__ void zero_i32(int* __restrict__ p, int n) {
    int i = blockIdx.x * blockDim.x + threadIdx.x;
    if (i < n) p[i] = 0;
}

// ---------------------------------------------------------------- GEMM1: h1 = x @ W1   [N,500]x[500,128] -> fp32
#define BM 64
#define BK 10
__global__ __launch_bounds__(256) void gemm1_kernel(
    const void* __restrict__ x, const void* __restrict__ W1,
    float* __restrict__ h1, int N, const int* __restrict__ dflag)
{
    const int isbf = *dflag;
    __shared__ float xs[BK][BM];      // transposed x tile
    __shared__ float wst[BK][HC];
    const int m0 = blockIdx.x * BM;
    const int tid = threadIdx.x;
    const int rb = (tid >> 5) << 3;   // 8 rows per thread
    const int cb = (tid & 31) << 2;   // 4 cols per thread

    float acc[8][4];
#pragma unroll
    for (int i = 0; i < 8; i++)
#pragma unroll
        for (int j = 0; j < 4; j++) acc[i][j] = 0.f;

    for (int k0 = 0; k0 < F_IN; k0 += BK) {
        for (int idx = tid; idx < BM * BK; idx += 256) {
            int r = idx / BK, kk = idx - r * BK;
            int row = m0 + r;
            xs[kk][r] = (row < N) ? ldf(x, (size_t)row * F_IN + k0 + kk, isbf) : 0.f;
        }
        for (int idx = tid; idx < BK * HC; idx += 256) {
            int kk = idx >> 7, c = idx & 127;
            wst[kk][c] = ldf(W1, (size_t)(k0 + kk) * HC + c, isbf);
        }
        __syncthreads();
#pragma unroll
        for (int kk = 0; kk < BK; ++kk) {
            float xv[8], wv[4];
#pragma unroll
            for (int i = 0; i < 8; i++) xv[i] = xs[kk][rb + i];
#pragma unroll
            for (int j = 0; j < 4; j++) wv[j] = wst[kk][cb + j];
#pragma unroll
            for (int i = 0; i < 8; i++)
#pragma unroll
                for (int j = 0; j < 4; j++) acc[i][j] += xv[i] * wv[j];
        }
        __syncthreads();
    }
#pragma unroll
    for (int i = 0; i < 8; i++) {
        int row = m0 + rb + i;
        if (row < N) {
#pragma unroll
            for (int j = 0; j < 4; j++)
                h1[(size_t)row * HC + cb + j] = acc[i][j];
        }
    }
}

// ---------------------------------------------------------------- per-node attention dots for layer 1
// d1[j*N*8 + n*8 + h] = sum_c h1[n,h,c] * a1[j,h,c]
__global__ void dots1_kernel(const float* __restrict__ h1,
                             const void* __restrict__ a1,
                             float* __restrict__ d1, int N,
                             const int* __restrict__ dflag)
{
    const int isbf = *dflag;
    int id = blockIdx.x * blockDim.x + threadIdx.x;
    if (id >= N * NHEAD) return;
    int n = id >> 3, h = id & 7;
    const float* hp = h1 + (size_t)n * HC + h * CDIM;
    float s0 = 0.f, s1 = 0.f, s2 = 0.f;
#pragma unroll
    for (int c = 0; c < CDIM; c++) {
        float v = hp[c];
        s0 += v * ldf(a1, (0 * NHEAD + h) * CDIM + c, isbf);
        s1 += v * ldf(a1, (1 * NHEAD + h) * CDIM + c, isbf);
        s2 += v * ldf(a1, (2 * NHEAD + h) * CDIM + c, isbf);
    }
    d1[id] = s0;
    d1[N * NHEAD + id] = s1;
    d1[2 * N * NHEAD + id] = s2;
}

// ---------------------------------------------------------------- CSR build: histogram by destination
__global__ void hist_kernel(const int* __restrict__ pidx, int* __restrict__ deg, int P) {
    int p = blockIdx.x * blockDim.x + threadIdx.x;
    if (p < P) atomicAdd(deg + pidx[p], 1);
}

// block-level exclusive scan (256/block), emits block sums
__global__ void scan1_kernel(const int* __restrict__ deg, int* __restrict__ start,
                             int* __restrict__ bsum, int N) {
    __shared__ int sh[256];
    int i = blockIdx.x * 256 + threadIdx.x;
    int v = (i < N) ? deg[i] : 0;
    sh[threadIdx.x] = v;
    __syncthreads();
#pragma unroll
    for (int off = 1; off < 256; off <<= 1) {
        int x = (threadIdx.x >= off) ? sh[threadIdx.x - off] : 0;
        __syncthreads();
        sh[threadIdx.x] += x;
        __syncthreads();
    }
    if (i < N) start[i] = sh[threadIdx.x] - v;   // exclusive
    if (threadIdx.x == 255) bsum[blockIdx.x] = sh[255];
}

// single-block scan of block sums (nb <= 512)
__global__ void scan2_kernel(int* __restrict__ bsum, int nb) {
    __shared__ int sh[512];
    int v = (threadIdx.x < nb) ? bsum[threadIdx.x] : 0;
    sh[threadIdx.x] = v;
    __syncthreads();
#pragma unroll
    for (int off = 1; off < 512; off <<= 1) {
        int x = (threadIdx.x >= off) ? sh[threadIdx.x - off] : 0;
        __syncthreads();
        sh[threadIdx.x] += x;
        __syncthreads();
    }
    if (threadIdx.x < nb) bsum[threadIdx.x] = sh[threadIdx.x] - v;  // exclusive
}

__global__ void scan3_kernel(int* __restrict__ start, const int* __restrict__ bsum, int N) {
    int i = blockIdx.x * 256 + threadIdx.x;
    if (i < N) start[i] += bsum[blockIdx.x];
}

__global__ void scatter_kernel(const int* __restrict__ pidx,
                               const int* __restrict__ start,
                               int* __restrict__ cursor,
                               int* __restrict__ csr, int P) {
    int p = blockIdx.x * blockDim.x + threadIdx.x;
    if (p >= P) return;
    int hd = pidx[p];
    int pos = atomicAdd(cursor + hd, 1);
    csr[start[hd] + pos] = p;
}

// ---------------------------------------------------------------- layer1 attention, CSR form.
// One wave (64 lanes) per node; lane j owns output cols 2j,2j+1 (head = j>>3).
// Phase 1: per-head max over this node's paths (registers, redundant per lane).
// Phase 2: acc += exp(e-mx) * h1[tail], den += exp. Then bias + ELU, one write.
__global__ __launch_bounds__(256) void attn1_csr_kernel(
    const int* __restrict__ csr, const int* __restrict__ start,
    const int* __restrict__ deg, const int* __restrict__ pidx,
    const float* __restrict__ d1, const float* __restrict__ h1,
    const void* __restrict__ b1, float* __restrict__ elu_out,
    int N, int P, const int* __restrict__ dflag)
{
    const int isbf = *dflag;
    int node = blockIdx.x * 4 + (threadIdx.x >> 6);
    if (node >= N) return;
    int lane = threadIdx.x & 63;
    int h = lane >> 3;
    int s0 = start[node], dg = deg[node];
    const float* d1m = d1 + (size_t)N * NHEAD;
    const float* d1t = d1 + (size_t)2 * N * NHEAD;
    const float dh = d1[node * NHEAD + h];

    float mx = -3.4e38f;
    for (int k = 0; k < dg; k++) {
        int p = csr[s0 + k];
        float e = dh + d1m[pidx[P + p] * NHEAD + h] + d1t[pidx[2 * P + p] * NHEAD + h];
        e = e > 0.f ? e : 0.2f * e;
        mx = fmaxf(mx, e);
    }
    float acc0 = 0.f, acc1 = 0.f, den = 0.f;
    for (int k = 0; k < dg; k++) {
        int p = csr[s0 + k];
        int tl = pidx[2 * P + p];
        float e = dh + d1m[pidx[P + p] * NHEAD + h] + d1t[tl * NHEAD + h];
        e = e > 0.f ? e : 0.2f * e;
        float ex = __expf(e - mx);
        den += ex;
        float2 v = *(const float2*)(h1 + (size_t)tl * HC + 2 * lane);
        acc0 += ex * v.x;
        acc1 += ex * v.y;
    }
    float inv = 1.f / (den + 1e-16f);
    int j0 = 2 * lane;
    float v0 = acc0 * inv + ldf(b1, j0, isbf);
    float v1 = acc1 * inv + ldf(b1, j0 + 1, isbf);
    v0 = v0 > 0.f ? v0 : __expf(v0) - 1.f;
    v1 = v1 > 0.f ? v1 : __expf(v1) - 1.f;
    *(float2*)(elu_out + (size_t)node * HC + j0) = make_float2(v0, v1);
}

// ---------------------------------------------------------------- layer2 GEMM + dots: h2 = elu @ W2 ; d2[j,n] = h2[n,:]·a2[j]
__global__ __launch_bounds__(256) void layer2_kernel(
    const float* __restrict__ elu, const void* __restrict__ W2,
    const void* __restrict__ a2,
    float* __restrict__ h2, float* __restrict__ d2, int N,
    const int* __restrict__ dflag)
{
    const int isbf = *dflag;
    __shared__ float rows[16][HC + 1];
    __shared__ float h2s[16][NCLS + 1];
    const int n0 = blockIdx.x * 16;
    const int tid = threadIdx.x;
    for (int idx = tid; idx < 16 * HC; idx += 256) {
        int r = idx >> 7, c = idx & 127;
        rows[r][c] = (n0 + r < N) ? elu[(size_t)(n0 + r) * HC + c] : 0.f;
    }
    __syncthreads();
    int ln = tid >> 4, c = tid & 15;
    float acc = 0.f;
#pragma unroll 8
    for (int j = 0; j < HC; j++) acc += rows[ln][j] * ldf(W2, (size_t)j * NCLS + c, isbf);
    h2s[ln][c] = acc;
    if (n0 + ln < N) h2[(size_t)(n0 + ln) * NCLS + c] = acc;
    __syncthreads();
    if (tid < 48) {
        int l = tid / 3, j = tid - l * 3;
        if (n0 + l < N) {
            float s = 0.f;
#pragma unroll
            for (int cc = 0; cc < NCLS; cc++) s += h2s[l][cc] * ldf(a2, j * NCLS + cc, isbf);
            d2[j * N + n0 + l] = s;
        }
    }
}

// ---------------------------------------------------------------- layer2 attention CSR + log_softmax, fused to output.
// 16 lanes per node (c = lane&15); softmax over paths in registers, then
// cross-lane (width 16) max/sum shuffles for log_softmax.
__global__ __launch_bounds__(256) void attn2_csr_kernel(
    const int* __restrict__ csr, const int* __restrict__ start,
    const int* __restrict__ deg, const int* __restrict__ pidx,
    const float* __restrict__ d2, const float* __restrict__ h2,
    const void* __restrict__ b2, void* __restrict__ out,
    int N, int P, const int* __restrict__ dflag)
{
    const int isbf = *dflag;
    int node = blockIdx.x * 16 + (threadIdx.x >> 4);
    if (node >= N) return;
    int c = threadIdx.x & 15;
    int s0 = start[node], dg = deg[node];
    const float dh = d2[node];
    const float* d2m = d2 + N;
    const float* d2t = d2 + 2 * N;

    float mx = -3.4e38f;
    for (int k = 0; k < dg; k++) {
        int p = csr[s0 + k];
        float e = dh + d2m[pidx[P + p]] + d2t[pidx[2 * P + p]];
        e = e > 0.f ? e : 0.2f * e;
        mx = fmaxf(mx, e);
    }
    float acc = 0.f, den = 0.f;
    for (int k = 0; k < dg; k++) {
        int p = csr[s0 + k];
        int tl = pidx[2 * P + p];
        float e = dh + d2m[pidx[P + p]] + d2t[tl];
        e = e > 0.f ? e : 0.2f * e;
        float ex = __expf(e - mx);
        den += ex;
        acc += ex * h2[(size_t)tl * NCLS + c];
    }
    float o = acc / (den + 1e-16f) + ldf(b2, c, isbf);
    // log_softmax across the 16 lanes of this node
    float m2 = o;
#pragma unroll
    for (int w = 1; w < 16; w <<= 1) m2 = fmaxf(m2, __shfl_xor(m2, w, 16));
    float ex = __expf(o - m2), sm = ex;
#pragma unroll
    for (int w = 1; w < 16; w <<= 1) sm += __shfl_xor(sm, w, 16);
    float r = o - m2 - __logf(sm);
    if (isbf) ((__hip_bfloat16*)out)[(size_t)node * NCLS + c] = __float2bfloat16(r);
    else      ((float*)out)[(size_t)node * NCLS + c] = r;
}

// ================================================================ launch
extern "C" void kernel_launch(void* const* d_in, const int* in_sizes, int n_in,
                              void* d_out, int out_size, void* d_ws, size_t ws_size,
                              hipStream_t stream)
{
    const void* x  = d_in[0];
    const int*  pi = (const int*)d_in[1];
    const void* W1 = d_in[2];
    const void* a1 = d_in[3];
    const void* b1 = d_in[4];
    const void* W2 = d_in[5];
    const void* a2 = d_in[6];
    const void* b2 = d_in[7];

    const int N = in_sizes[0] / F_IN;   // 100000
    const int P = in_sizes[1] / 3;      // 1000000

    float* ws = (float*)d_ws;
    // workspace layout (float units) — peak ~302N + P + 2050 floats (~125 MB)
    size_t off_h1     = 0;                        // 128N
    size_t off_d1     = (size_t)128 * N;          // 24N
    size_t off_elu    = (size_t)152 * N;          // 128N
    size_t off_h2     = (size_t)280 * N;          // 16N
    size_t off_d2     = (size_t)296 * N;          // 3N
    size_t off_deg    = (size_t)299 * N;          // N (int)
    size_t off_start  = (size_t)300 * N;          // N (int)
    size_t off_cursor = (size_t)301 * N;          // N (int)
    size_t off_bsum   = (size_t)302 * N;          // 1024 (int)
    size_t off_csr    = (size_t)302 * N + 1024;   // P (int)
    size_t off_flag   = (size_t)302 * N + 1024 + P; // 1

    float* h1   = ws + off_h1;
    float* d1   = ws + off_d1;
    float* elu  = ws + off_elu;
    float* h2   = ws + off_h2;
    float* d2   = ws + off_d2;
    int* deg    = (int*)(ws + off_deg);
    int* start  = (int*)(ws + off_start);
    int* cursor = (int*)(ws + off_cursor);
    int* bsum   = (int*)(ws + off_bsum);
    int* csr    = (int*)(ws + off_csr);
    int* dflag  = (int*)(ws + off_flag);

    const int BLK = 256;
    const int nb = (N + 255) / 256;   // scan blocks (must be <= 512)

    detect_dtype_kernel<<<1, 256, 0, stream>>>((const unsigned short*)x, dflag);
    // zero deg..cursor (3N ints; start overwritten by scan anyway)
    zero_i32<<<(3 * N + BLK - 1) / BLK, BLK, 0, stream>>>(deg, 3 * N);
    gemm1_kernel<<<(N + BM - 1) / BM, 256, 0, stream>>>(x, W1, h1, N, dflag);
    dots1_kernel<<<(N * NHEAD + BLK - 1) / BLK, BLK, 0, stream>>>(h1, a1, d1, N, dflag);
    // CSR build
    hist_kernel<<<(P + BLK - 1) / BLK, BLK, 0, stream>>>(pi, deg, P);
    scan1_kernel<<<nb, 256, 0, stream>>>(deg, start, bsum, N);
    scan2_kernel<<<1, 512, 0, stream>>>(bsum, nb);
    scan3_kernel<<<nb, 256, 0, stream>>>(start, bsum, N);
    scatter_kernel<<<(P + BLK - 1) / BLK, BLK, 0, stream>>>(pi, start, cursor, csr, P);
    // layer 1 attention (fused max/softmax/aggregate/bias/elu)
    attn1_csr_kernel<<<(N + 3) / 4, 256, 0, stream>>>(csr, start, deg, pi, d1, h1, b1, elu, N, P, dflag);
    // layer 2
    layer2_kernel<<<(N + 15) / 16, 256, 0, stream>>>(elu, W2, a2, h2, d2, N, dflag);
    attn2_csr_kernel<<<(N + 15) / 16, 256, 0, stream>>>(csr, start, deg, pi, d2, h2, b2, d_out, N, P, dflag);
}

// Round 5
// 901.369 us; speedup vs baseline: 1.5193x; 1.1804x over previous
//
#include <hip/hip_runtime.h>
#include <hip/hip_bf16.h>

// Problem constants (shapes fixed by setup_inputs). All float I/O is fp32
// (established round 4: hardcoded-bf16 reads NaN'd twice; flag-version passed).
#define F_IN  500
#define HC    128   // H*C
#define NHEAD 8
#define CDIM  16
#define NCLS  16
#define KPAD  512   // F_IN padded to multiple of 32 for MFMA K-loop

static __device__ __forceinline__ float bf(const __hip_bfloat16 v) {
    return __bfloat162float(v);
}

typedef __bf16 bf16x8 __attribute__((ext_vector_type(8)));
typedef float f32x4 __attribute__((ext_vector_type(4)));

// ---------------------------------------------------------------- zero fill (ints)
__global__ void zero_i32(int* __restrict__ p, int n) {
    int i = blockIdx.x * blockDim.x + threadIdx.x;
    if (i < n) p[i] = 0;
}

// ---------------------------------------------------------------- W1^T prep:
// w1t_hi[c][k] = bf16(W1[k][c]), w1t_lo = bf16(residual); zero-padded k>=500.
__global__ void transpose_w1(const float* __restrict__ W1,
                             __bf16* __restrict__ w1t_hi,
                             __bf16* __restrict__ w1t_lo)
{
    int id = blockIdx.x * 256 + threadIdx.x;   // 128*512
    int c = id >> 9, k = id & 511;
    float v = (k < F_IN) ? W1[k * HC + c] : 0.f;
    __bf16 h = (__bf16)v;
    w1t_hi[id] = h;
    w1t_lo[id] = (__bf16)(v - (float)h);
}

// split 8 fp32 into bf16 hi + bf16 lo fragments
static __device__ __forceinline__ void split8(const float4 a, const float4 b,
                                              bf16x8& hi, bf16x8& lo) {
    float v[8] = {a.x, a.y, a.z, a.w, b.x, b.y, b.z, b.w};
#pragma unroll
    for (int j = 0; j < 8; j++) {
        __bf16 h = (__bf16)v[j];
        hi[j] = h;
        lo[j] = (__bf16)(v[j] - (float)h);
    }
}

// ---------------------------------------------------------------- GEMM1 (MFMA, split-bf16):
// h1 = x @ W1 -> bf16 [N,128]. Wave computes 32 rows x 128 cols. A streamed
// from global fp32 (read once) and split hi/lo in-register; B from L2-resident
// split W1^T. acc += Ah*Bh + Ah*Bl + Al*Bh  (error ~ lo*lo ~ 2^-16 rel).
__global__ __launch_bounds__(256) void gemm1_mfma(
    const float* __restrict__ x,
    const __bf16* __restrict__ w1t_hi, const __bf16* __restrict__ w1t_lo,
    __hip_bfloat16* __restrict__ h1, int N)
{
    const int wave = threadIdx.x >> 6, lane = threadIdx.x & 63;
    const int m = lane & 15, q = lane >> 4;
    const int row0 = blockIdx.x * 128 + wave * 32;

    long ra0 = row0 + m, ra1 = row0 + 16 + m;
    if (ra0 >= N) ra0 = 0;
    if (ra1 >= N) ra1 = 0;
    const float* pa0 = x + ra0 * F_IN + q * 8;
    const float* pa1 = x + ra1 * F_IN + q * 8;
    const __bf16* pbh = w1t_hi + (size_t)m * KPAD + q * 8;
    const __bf16* pbl = w1t_lo + (size_t)m * KPAD + q * 8;

    f32x4 acc[2][8];
#pragma unroll
    for (int i = 0; i < 2; i++)
#pragma unroll
        for (int t = 0; t < 8; t++) acc[i][t] = (f32x4){0.f, 0.f, 0.f, 0.f};

    // main K steps: k0 = 0..448 (max k touched = 448+31 = 479 < 500)
#pragma unroll
    for (int k0 = 0; k0 < 480; k0 += 32) {
        bf16x8 a0h, a0l, a1h, a1l;
        split8(*(const float4*)(pa0 + k0), *(const float4*)(pa0 + k0 + 4), a0h, a0l);
        split8(*(const float4*)(pa1 + k0), *(const float4*)(pa1 + k0 + 4), a1h, a1l);
#pragma unroll
        for (int t = 0; t < 8; t++) {
            bf16x8 bh = *(const bf16x8*)(pbh + t * 16 * KPAD + k0);
            bf16x8 bl = *(const bf16x8*)(pbl + t * 16 * KPAD + k0);
            acc[0][t] = __builtin_amdgcn_mfma_f32_16x16x32_bf16(a0h, bh, acc[0][t], 0, 0, 0);
            acc[0][t] = __builtin_amdgcn_mfma_f32_16x16x32_bf16(a0h, bl, acc[0][t], 0, 0, 0);
            acc[0][t] = __builtin_amdgcn_mfma_f32_16x16x32_bf16(a0l, bh, acc[0][t], 0, 0, 0);
            acc[1][t] = __builtin_amdgcn_mfma_f32_16x16x32_bf16(a1h, bh, acc[1][t], 0, 0, 0);
            acc[1][t] = __builtin_amdgcn_mfma_f32_16x16x32_bf16(a1h, bl, acc[1][t], 0, 0, 0);
            acc[1][t] = __builtin_amdgcn_mfma_f32_16x16x32_bf16(a1l, bh, acc[1][t], 0, 0, 0);
        }
    }
    // epilogue K step k0=480: lanes with k>=500 masked (W1^T already 0 there)
    {
        const float4 z4 = make_float4(0.f, 0.f, 0.f, 0.f);
        bf16x8 a0h, a0l, a1h, a1l;
        float4 u0 = (q < 3) ? *(const float4*)(pa0 + 480) : z4;
        float4 u1 = (q < 2) ? *(const float4*)(pa0 + 484) : z4;
        float4 w0 = (q < 3) ? *(const float4*)(pa1 + 480) : z4;
        float4 w1 = (q < 2) ? *(const float4*)(pa1 + 484) : z4;
        split8(u0, u1, a0h, a0l);
        split8(w0, w1, a1h, a1l);
#pragma unroll
        for (int t = 0; t < 8; t++) {
            bf16x8 bh = *(const bf16x8*)(pbh + t * 16 * KPAD + 480);
            bf16x8 bl = *(const bf16x8*)(pbl + t * 16 * KPAD + 480);
            acc[0][t] = __builtin_amdgcn_mfma_f32_16x16x32_bf16(a0h, bh, acc[0][t], 0, 0, 0);
            acc[0][t] = __builtin_amdgcn_mfma_f32_16x16x32_bf16(a0h, bl, acc[0][t], 0, 0, 0);
            acc[0][t] = __builtin_amdgcn_mfma_f32_16x16x32_bf16(a0l, bh, acc[0][t], 0, 0, 0);
            acc[1][t] = __builtin_amdgcn_mfma_f32_16x16x32_bf16(a1h, bh, acc[1][t], 0, 0, 0);
            acc[1][t] = __builtin_amdgcn_mfma_f32_16x16x32_bf16(a1h, bl, acc[1][t], 0, 0, 0);
            acc[1][t] = __builtin_amdgcn_mfma_f32_16x16x32_bf16(a1l, bh, acc[1][t], 0, 0, 0);
        }
    }
    // store: C/D layout col=lane&15, row=(lane>>4)*4+reg
#pragma unroll
    for (int rt = 0; rt < 2; rt++) {
        int rbase = row0 + rt * 16 + q * 4;
#pragma unroll
        for (int t = 0; t < 8; t++) {
#pragma unroll
            for (int r = 0; r < 4; r++) {
                int row = rbase + r;
                if (row < N)
                    h1[(size_t)row * HC + t * 16 + m] = __float2bfloat16(acc[rt][t][r]);
            }
        }
    }
}

// ---------------------------------------------------------------- per-node attention dots for layer 1
// d1[j*N*8 + n*8 + h] = sum_c h1[n,h,c] * a1[j,h,c]
__global__ void dots1_kernel(const __hip_bfloat16* __restrict__ h1,
                             const float* __restrict__ a1,
                             float* __restrict__ d1, int N)
{
    int id = blockIdx.x * blockDim.x + threadIdx.x;
    if (id >= N * NHEAD) return;
    int n = id >> 3, h = id & 7;
    const __hip_bfloat16* hp = h1 + (size_t)n * HC + h * CDIM;
    float s0 = 0.f, s1 = 0.f, s2 = 0.f;
#pragma unroll
    for (int c = 0; c < CDIM; c++) {
        float v = bf(hp[c]);
        s0 += v * a1[(0 * NHEAD + h) * CDIM + c];
        s1 += v * a1[(1 * NHEAD + h) * CDIM + c];
        s2 += v * a1[(2 * NHEAD + h) * CDIM + c];
    }
    d1[id] = s0;
    d1[N * NHEAD + id] = s1;
    d1[2 * N * NHEAD + id] = s2;
}

// ---------------------------------------------------------------- CSR build
__global__ void hist_kernel(const int* __restrict__ pidx, int* __restrict__ deg, int P) {
    int p = blockIdx.x * blockDim.x + threadIdx.x;
    if (p < P) atomicAdd(deg + pidx[p], 1);
}

__global__ void scan1_kernel(const int* __restrict__ deg, int* __restrict__ start,
                             int* __restrict__ bsum, int N) {
    __shared__ int sh[256];
    int i = blockIdx.x * 256 + threadIdx.x;
    int v = (i < N) ? deg[i] : 0;
    sh[threadIdx.x] = v;
    __syncthreads();
#pragma unroll
    for (int off = 1; off < 256; off <<= 1) {
        int x = (threadIdx.x >= off) ? sh[threadIdx.x - off] : 0;
        __syncthreads();
        sh[threadIdx.x] += x;
        __syncthreads();
    }
    if (i < N) start[i] = sh[threadIdx.x] - v;   // exclusive
    if (threadIdx.x == 255) bsum[blockIdx.x] = sh[255];
}

__global__ void scan2_kernel(int* __restrict__ bsum, int nb) {
    __shared__ int sh[512];
    int v = (threadIdx.x < nb) ? bsum[threadIdx.x] : 0;
    sh[threadIdx.x] = v;
    __syncthreads();
#pragma unroll
    for (int off = 1; off < 512; off <<= 1) {
        int x = (threadIdx.x >= off) ? sh[threadIdx.x - off] : 0;
        __syncthreads();
        sh[threadIdx.x] += x;
        __syncthreads();
    }
    if (threadIdx.x < nb) bsum[threadIdx.x] = sh[threadIdx.x] - v;  // exclusive
}

__global__ void scan3_kernel(int* __restrict__ start, const int* __restrict__ bsum, int N) {
    int i = blockIdx.x * 256 + threadIdx.x;
    if (i < N) start[i] += bsum[blockIdx.x];
}

__global__ void scatter_kernel(const int* __restrict__ pidx,
                               const int* __restrict__ start,
                               int* __restrict__ cursor,
                               int* __restrict__ csr, int P) {
    int p = blockIdx.x * blockDim.x + threadIdx.x;
    if (p >= P) return;
    int hd = pidx[p];
    int pos = atomicAdd(cursor + hd, 1);
    csr[start[hd] + pos] = p;
}

// ---------------------------------------------------------------- layer1 attention, CSR form (one wave per node)
__global__ __launch_bounds__(256) void attn1_csr_kernel(
    const int* __restrict__ csr, const int* __restrict__ start,
    const int* __restrict__ deg, const int* __restrict__ pidx,
    const float* __restrict__ d1, const __hip_bfloat16* __restrict__ h1,
    const float* __restrict__ b1, float* __restrict__ elu_out,
    int N, int P)
{
    int node = blockIdx.x * 4 + (threadIdx.x >> 6);
    if (node >= N) return;
    int lane = threadIdx.x & 63;
    int h = lane >> 3;
    int s0 = start[node], dg = deg[node];
    const float* d1m = d1 + (size_t)N * NHEAD;
    const float* d1t = d1 + (size_t)2 * N * NHEAD;
    const float dh = d1[node * NHEAD + h];

    float mx = -3.4e38f;
    for (int k = 0; k < dg; k++) {
        int p = csr[s0 + k];
        float e = dh + d1m[pidx[P + p] * NHEAD + h] + d1t[pidx[2 * P + p] * NHEAD + h];
        e = e > 0.f ? e : 0.2f * e;
        mx = fmaxf(mx, e);
    }
    float acc0 = 0.f, acc1 = 0.f, den = 0.f;
    for (int k = 0; k < dg; k++) {
        int p = csr[s0 + k];
        int tl = pidx[2 * P + p];
        float e = dh + d1m[pidx[P + p] * NHEAD + h] + d1t[tl * NHEAD + h];
        e = e > 0.f ? e : 0.2f * e;
        float ex = __expf(e - mx);
        den += ex;
        __hip_bfloat162 v = *(const __hip_bfloat162*)(h1 + (size_t)tl * HC + 2 * lane);
        acc0 += ex * bf(v.x);
        acc1 += ex * bf(v.y);
    }
    float inv = 1.f / (den + 1e-16f);
    int j0 = 2 * lane;
    float v0 = acc0 * inv + b1[j0];
    float v1 = acc1 * inv + b1[j0 + 1];
    v0 = v0 > 0.f ? v0 : __expf(v0) - 1.f;
    v1 = v1 > 0.f ? v1 : __expf(v1) - 1.f;
    *(float2*)(elu_out + (size_t)node * HC + j0) = make_float2(v0, v1);
}

// ---------------------------------------------------------------- layer2 GEMM + dots: h2 = elu @ W2 ; d2[j,n] = h2[n,:]·a2[j]
__global__ __launch_bounds__(256) void layer2_kernel(
    const float* __restrict__ elu, const float* __restrict__ W2,
    const float* __restrict__ a2,
    float* __restrict__ h2, float* __restrict__ d2, int N)
{
    __shared__ float rows[16][HC + 1];
    __shared__ float h2s[16][NCLS + 1];
    const int n0 = blockIdx.x * 16;
    const int tid = threadIdx.x;
    for (int idx = tid; idx < 16 * HC; idx += 256) {
        int r = idx >> 7, c = idx & 127;
        rows[r][c] = (n0 + r < N) ? elu[(size_t)(n0 + r) * HC + c] : 0.f;
    }
    __syncthreads();
    int ln = tid >> 4, c = tid & 15;
    float acc = 0.f;
#pragma unroll 8
    for (int j = 0; j < HC; j++) acc += rows[ln][j] * W2[j * NCLS + c];
    h2s[ln][c] = acc;
    if (n0 + ln < N) h2[(size_t)(n0 + ln) * NCLS + c] = acc;
    __syncthreads();
    if (tid < 48) {
        int l = tid / 3, j = tid - l * 3;
        if (n0 + l < N) {
            float s = 0.f;
#pragma unroll
            for (int cc = 0; cc < NCLS; cc++) s += h2s[l][cc] * a2[j * NCLS + cc];
            d2[j * N + n0 + l] = s;
        }
    }
}

// ---------------------------------------------------------------- layer2 attention CSR + log_softmax, fused to output (fp32)
__global__ __launch_bounds__(256) void attn2_csr_kernel(
    const int* __restrict__ csr, const int* __restrict__ start,
    const int* __restrict__ deg, const int* __restrict__ pidx,
    const float* __restrict__ d2, const float* __restrict__ h2,
    const float* __restrict__ b2, float* __restrict__ out,
    int N, int P)
{
    int node = blockIdx.x * 16 + (threadIdx.x >> 4);
    if (node >= N) return;
    int c = threadIdx.x & 15;
    int s0 = start[node], dg = deg[node];
    const float dh = d2[node];
    const float* d2m = d2 + N;
    const float* d2t = d2 + 2 * N;

    float mx = -3.4e38f;
    for (int k = 0; k < dg; k++) {
        int p = csr[s0 + k];
        float e = dh + d2m[pidx[P + p]] + d2t[pidx[2 * P + p]];
        e = e > 0.f ? e : 0.2f * e;
        mx = fmaxf(mx, e);
    }
    float acc = 0.f, den = 0.f;
    for (int k = 0; k < dg; k++) {
        int p = csr[s0 + k];
        int tl = pidx[2 * P + p];
        float e = dh + d2m[pidx[P + p]] + d2t[tl];
        e = e > 0.f ? e : 0.2f * e;
        float ex = __expf(e - mx);
        den += ex;
        acc += ex * h2[(size_t)tl * NCLS + c];
    }
    float o = acc / (den + 1e-16f) + b2[c];
    // log_softmax across the 16 lanes of this node
    float m2 = o;
#pragma unroll
    for (int w = 1; w < 16; w <<= 1) m2 = fmaxf(m2, __shfl_xor(m2, w, 16));
    float ex = __expf(o - m2), sm = ex;
#pragma unroll
    for (int w = 1; w < 16; w <<= 1) sm += __shfl_xor(sm, w, 16);
    float r = o - m2 - __logf(sm);
    out[(size_t)node * NCLS + c] = r;
}

// ================================================================ launch
extern "C" void kernel_launch(void* const* d_in, const int* in_sizes, int n_in,
                              void* d_out, int out_size, void* d_ws, size_t ws_size,
                              hipStream_t stream)
{
    const float* x  = (const float*)d_in[0];
    const int*   pi = (const int*)d_in[1];
    const float* W1 = (const float*)d_in[2];
    const float* a1 = (const float*)d_in[3];
    const float* b1 = (const float*)d_in[4];
    const float* W2 = (const float*)d_in[5];
    const float* a2 = (const float*)d_in[6];
    const float* b2 = (const float*)d_in[7];

    const int N = in_sizes[0] / F_IN;   // 100000
    const int P = in_sizes[1] / 3;      // 1000000

    float* ws = (float*)d_ws;
    // workspace (float units): peak ~238N + P + 66k floats (~99.5 MB)
    size_t off_h1     = 0;                          // 64N  (bf16 x 128N)
    size_t off_d1     = (size_t)64 * N;             // 24N
    size_t off_elu    = (size_t)88 * N;             // 128N
    size_t off_h2     = (size_t)216 * N;            // 16N
    size_t off_d2     = (size_t)232 * N;            // 3N
    size_t off_deg    = (size_t)235 * N;            // N (int)
    size_t off_start  = (size_t)236 * N;            // N (int)
    size_t off_cursor = (size_t)237 * N;            // N (int)
    size_t off_bsum   = (size_t)238 * N;            // 1024 (int)
    size_t off_csr    = (size_t)238 * N + 1024;     // P (int)
    size_t off_w1th   = (size_t)238 * N + 1024 + P; // 32768 (bf16 x 65536)
    size_t off_w1tl   = off_w1th + 32768;           // 32768

    __hip_bfloat16* h1 = (__hip_bfloat16*)(ws + off_h1);
    float* d1   = ws + off_d1;
    float* elu  = ws + off_elu;
    float* h2   = ws + off_h2;
    float* d2   = ws + off_d2;
    int* deg    = (int*)(ws + off_deg);
    int* start  = (int*)(ws + off_start);
    int* cursor = (int*)(ws + off_cursor);
    int* bsum   = (int*)(ws + off_bsum);
    int* csr    = (int*)(ws + off_csr);
    __bf16* w1t_hi = (__bf16*)(ws + off_w1th);
    __bf16* w1t_lo = (__bf16*)(ws + off_w1tl);

    const int BLK = 256;
    const int nb = (N + 255) / 256;   // scan blocks (<= 512)

    transpose_w1<<<(HC * KPAD) / 256, 256, 0, stream>>>(W1, w1t_hi, w1t_lo);
    zero_i32<<<(3 * N + BLK - 1) / BLK, BLK, 0, stream>>>(deg, 3 * N);
    gemm1_mfma<<<(N + 127) / 128, 256, 0, stream>>>(x, w1t_hi, w1t_lo, h1, N);
    dots1_kernel<<<(N * NHEAD + BLK - 1) / BLK, BLK, 0, stream>>>(h1, a1, d1, N);
    // CSR build
    hist_kernel<<<(P + BLK - 1) / BLK, BLK, 0, stream>>>(pi, deg, P);
    scan1_kernel<<<nb, 256, 0, stream>>>(deg, start, bsum, N);
    scan2_kernel<<<1, 512, 0, stream>>>(bsum, nb);
    scan3_kernel<<<nb, 256, 0, stream>>>(start, bsum, N);
    scatter_kernel<<<(P + BLK - 1) / BLK, BLK, 0, stream>>>(pi, start, cursor, csr, P);
    // layer 1 attention (fused max/softmax/aggregate/bias/elu)
    attn1_csr_kernel<<<(N + 3) / 4, 256, 0, stream>>>(csr, start, deg, pi, d1, h1, b1, elu, N, P);
    // layer 2
    layer2_kernel<<<(N + 15) / 16, 256, 0, stream>>>(elu, W2, a2, h2, d2, N);
    attn2_csr_kernel<<<(N + 15) / 16, 256, 0, stream>>>(csr, start, deg, pi, d2, h2, b2,
                                                        (float*)d_out, N, P);
}

// Round 6
// 747.854 us; speedup vs baseline: 1.8312x; 1.2053x over previous
//
#include <hip/hip_runtime.h>
#include <hip/hip_bf16.h>

// Problem constants (shapes fixed by setup_inputs). All float I/O is fp32
// (established round 4: hardcoded-bf16 reads NaN'd twice; flag-version passed).
#define F_IN  500
#define HC    128   // H*C
#define NHEAD 8
#define CDIM  16
#define NCLS  16
#define KPAD  512   // F_IN padded to multiple of 32 for MFMA K-loop

static __device__ __forceinline__ float bf(const __hip_bfloat16 v) {
    return __bfloat162float(v);
}

// ordered-uint encoding for float atomicMax
static __device__ __forceinline__ unsigned int enc_f32(float f) {
    unsigned int u = __float_as_uint(f);
    return (u & 0x80000000u) ? ~u : (u | 0x80000000u);
}
static __device__ __forceinline__ float dec_f32(unsigned int u) {
    return __uint_as_float((u & 0x80000000u) ? (u & 0x7FFFFFFFu) : ~u);
}

typedef __bf16 bf16x8 __attribute__((ext_vector_type(8)));
typedef float f32x4 __attribute__((ext_vector_type(4)));

// ---------------------------------------------------------------- zero fill (ints)
__global__ void zero_i32(int* __restrict__ p, int n) {
    int i = blockIdx.x * blockDim.x + threadIdx.x;
    if (i < n) p[i] = 0;
}

// ---------------------------------------------------------------- W1^T prep:
// w1t_hi[c][k] = bf16(W1[k][c]), w1t_lo = bf16(residual); zero-padded k>=500.
__global__ void transpose_w1(const float* __restrict__ W1,
                             __bf16* __restrict__ w1t_hi,
                             __bf16* __restrict__ w1t_lo)
{
    int id = blockIdx.x * 256 + threadIdx.x;   // 128*512
    int c = id >> 9, k = id & 511;
    float v = (k < F_IN) ? W1[k * HC + c] : 0.f;
    __bf16 h = (__bf16)v;
    w1t_hi[id] = h;
    w1t_lo[id] = (__bf16)(v - (float)h);
}

// split 8 fp32 into bf16 hi + bf16 lo fragments
static __device__ __forceinline__ void split8(const float4 a, const float4 b,
                                              bf16x8& hi, bf16x8& lo) {
    float v[8] = {a.x, a.y, a.z, a.w, b.x, b.y, b.z, b.w};
#pragma unroll
    for (int j = 0; j < 8; j++) {
        __bf16 h = (__bf16)v[j];
        hi[j] = h;
        lo[j] = (__bf16)(v[j] - (float)h);
    }
}

// ---------------------------------------------------------------- GEMM1 (MFMA, split-bf16):
// h1 = x @ W1 -> bf16 [N,128]. Wave computes 32 rows x 128 cols. A streamed
// from global fp32 (read once) and split hi/lo in-register; B from L2-resident
// split W1^T. acc += Ah*Bh + Ah*Bl + Al*Bh  (error ~ lo*lo ~ 2^-16 rel).
__global__ __launch_bounds__(256) void gemm1_mfma(
    const float* __restrict__ x,
    const __bf16* __restrict__ w1t_hi, const __bf16* __restrict__ w1t_lo,
    __hip_bfloat16* __restrict__ h1, int N)
{
    const int wave = threadIdx.x >> 6, lane = threadIdx.x & 63;
    const int m = lane & 15, q = lane >> 4;
    const int row0 = blockIdx.x * 128 + wave * 32;

    long ra0 = row0 + m, ra1 = row0 + 16 + m;
    if (ra0 >= N) ra0 = 0;
    if (ra1 >= N) ra1 = 0;
    const float* pa0 = x + ra0 * F_IN + q * 8;
    const float* pa1 = x + ra1 * F_IN + q * 8;
    const __bf16* pbh = w1t_hi + (size_t)m * KPAD + q * 8;
    const __bf16* pbl = w1t_lo + (size_t)m * KPAD + q * 8;

    f32x4 acc[2][8];
#pragma unroll
    for (int i = 0; i < 2; i++)
#pragma unroll
        for (int t = 0; t < 8; t++) acc[i][t] = (f32x4){0.f, 0.f, 0.f, 0.f};

    // main K steps: k0 = 0..448 (max k touched = 448+31 = 479 < 500)
#pragma unroll
    for (int k0 = 0; k0 < 480; k0 += 32) {
        bf16x8 a0h, a0l, a1h, a1l;
        split8(*(const float4*)(pa0 + k0), *(const float4*)(pa0 + k0 + 4), a0h, a0l);
        split8(*(const float4*)(pa1 + k0), *(const float4*)(pa1 + k0 + 4), a1h, a1l);
#pragma unroll
        for (int t = 0; t < 8; t++) {
            bf16x8 bh = *(const bf16x8*)(pbh + t * 16 * KPAD + k0);
            bf16x8 bl = *(const bf16x8*)(pbl + t * 16 * KPAD + k0);
            acc[0][t] = __builtin_amdgcn_mfma_f32_16x16x32_bf16(a0h, bh, acc[0][t], 0, 0, 0);
            acc[0][t] = __builtin_amdgcn_mfma_f32_16x16x32_bf16(a0h, bl, acc[0][t], 0, 0, 0);
            acc[0][t] = __builtin_amdgcn_mfma_f32_16x16x32_bf16(a0l, bh, acc[0][t], 0, 0, 0);
            acc[1][t] = __builtin_amdgcn_mfma_f32_16x16x32_bf16(a1h, bh, acc[1][t], 0, 0, 0);
            acc[1][t] = __builtin_amdgcn_mfma_f32_16x16x32_bf16(a1h, bl, acc[1][t], 0, 0, 0);
            acc[1][t] = __builtin_amdgcn_mfma_f32_16x16x32_bf16(a1l, bh, acc[1][t], 0, 0, 0);
        }
    }
    // epilogue K step k0=480: lanes with k>=500 masked (W1^T already 0 there)
    {
        const float4 z4 = make_float4(0.f, 0.f, 0.f, 0.f);
        bf16x8 a0h, a0l, a1h, a1l;
        float4 u0 = (q < 3) ? *(const float4*)(pa0 + 480) : z4;
        float4 u1 = (q < 2) ? *(const float4*)(pa0 + 484) : z4;
        float4 w0 = (q < 3) ? *(const float4*)(pa1 + 480) : z4;
        float4 w1 = (q < 2) ? *(const float4*)(pa1 + 484) : z4;
        split8(u0, u1, a0h, a0l);
        split8(w0, w1, a1h, a1l);
#pragma unroll
        for (int t = 0; t < 8; t++) {
            bf16x8 bh = *(const bf16x8*)(pbh + t * 16 * KPAD + 480);
            bf16x8 bl = *(const bf16x8*)(pbl + t * 16 * KPAD + 480);
            acc[0][t] = __builtin_amdgcn_mfma_f32_16x16x32_bf16(a0h, bh, acc[0][t], 0, 0, 0);
            acc[0][t] = __builtin_amdgcn_mfma_f32_16x16x32_bf16(a0h, bl, acc[0][t], 0, 0, 0);
            acc[0][t] = __builtin_amdgcn_mfma_f32_16x16x32_bf16(a0l, bh, acc[0][t], 0, 0, 0);
            acc[1][t] = __builtin_amdgcn_mfma_f32_16x16x32_bf16(a1h, bh, acc[1][t], 0, 0, 0);
            acc[1][t] = __builtin_amdgcn_mfma_f32_16x16x32_bf16(a1h, bl, acc[1][t], 0, 0, 0);
            acc[1][t] = __builtin_amdgcn_mfma_f32_16x16x32_bf16(a1l, bh, acc[1][t], 0, 0, 0);
        }
    }
    // store: C/D layout col=lane&15, row=(lane>>4)*4+reg
#pragma unroll
    for (int rt = 0; rt < 2; rt++) {
        int rbase = row0 + rt * 16 + q * 4;
#pragma unroll
        for (int t = 0; t < 8; t++) {
#pragma unroll
            for (int r = 0; r < 4; r++) {
                int row = rbase + r;
                if (row < N)
                    h1[(size_t)row * HC + t * 16 + m] = __float2bfloat16(acc[rt][t][r]);
            }
        }
    }
}

// ---------------------------------------------------------------- per-node attention dots for layer 1
// d1[j*N*8 + n*8 + h] = sum_c h1[n,h,c] * a1[j,h,c]
__global__ void dots1_kernel(const __hip_bfloat16* __restrict__ h1,
                             const float* __restrict__ a1,
                             float* __restrict__ d1, int N)
{
    int id = blockIdx.x * blockDim.x + threadIdx.x;
    if (id >= N * NHEAD) return;
    int n = id >> 3, h = id & 7;
    const __hip_bfloat16* hp = h1 + (size_t)n * HC + h * CDIM;
    float s0 = 0.f, s1 = 0.f, s2 = 0.f;
#pragma unroll
    for (int c = 0; c < CDIM; c++) {
        float v = bf(hp[c]);
        s0 += v * a1[(0 * NHEAD + h) * CDIM + c];
        s1 += v * a1[(1 * NHEAD + h) * CDIM + c];
        s2 += v * a1[(2 * NHEAD + h) * CDIM + c];
    }
    d1[id] = s0;
    d1[N * NHEAD + id] = s1;
    d1[2 * N * NHEAD + id] = s2;
}

// ---------------------------------------------------------------- global maxima of d1m/d1t per head
// gmax[h] = max_n d1m[n,h]; gmax[8+h] = max_n d1t[n,h]  (ordered-uint encoded)
__global__ void maxred_d1(const float* __restrict__ d1,
                          unsigned int* __restrict__ gmax, int N)
{
    __shared__ unsigned int sm[16];
    if (threadIdx.x < 16) sm[threadIdx.x] = 0;
    __syncthreads();
    int total = 2 * N * NHEAD;
    for (int i = blockIdx.x * blockDim.x + threadIdx.x; i < total;
         i += gridDim.x * blockDim.x) {
        float v = d1[(size_t)N * NHEAD + i];   // d1m region then d1t region
        int slot = ((i >= N * NHEAD) ? 8 : 0) + (i & 7);
        atomicMax(&sm[slot], enc_f32(v));
    }
    __syncthreads();
    if (threadIdx.x < 16) atomicMax(&gmax[threadIdx.x], sm[threadIdx.x]);
}

// gmax2[0] = max_n d2m[n]; gmax2[1] = max_n d2t[n]
__global__ void maxred_d2(const float* __restrict__ d2,
                          unsigned int* __restrict__ gmax2, int N)
{
    __shared__ unsigned int sm[2];
    if (threadIdx.x < 2) sm[threadIdx.x] = 0;
    __syncthreads();
    int total = 2 * N;
    for (int i = blockIdx.x * blockDim.x + threadIdx.x; i < total;
         i += gridDim.x * blockDim.x) {
        float v = d2[N + i];
        atomicMax(&sm[i >= N ? 1 : 0], enc_f32(v));
    }
    __syncthreads();
    if (threadIdx.x < 2) atomicMax(&gmax2[threadIdx.x], sm[threadIdx.x]);
}

// ---------------------------------------------------------------- CSR build
__global__ void hist_kernel(const int* __restrict__ pidx, int* __restrict__ deg, int P) {
    int p = blockIdx.x * blockDim.x + threadIdx.x;
    if (p < P) atomicAdd(deg + pidx[p], 1);
}

__global__ void scan1_kernel(const int* __restrict__ deg, int* __restrict__ start,
                             int* __restrict__ bsum, int N) {
    __shared__ int sh[256];
    int i = blockIdx.x * 256 + threadIdx.x;
    int v = (i < N) ? deg[i] : 0;
    sh[threadIdx.x] = v;
    __syncthreads();
#pragma unroll
    for (int off = 1; off < 256; off <<= 1) {
        int x = (threadIdx.x >= off) ? sh[threadIdx.x - off] : 0;
        __syncthreads();
        sh[threadIdx.x] += x;
        __syncthreads();
    }
    if (i < N) start[i] = sh[threadIdx.x] - v;   // exclusive
    if (threadIdx.x == 255) bsum[blockIdx.x] = sh[255];
}

__global__ void scan2_kernel(int* __restrict__ bsum, int nb) {
    __shared__ int sh[512];
    int v = (threadIdx.x < nb) ? bsum[threadIdx.x] : 0;
    sh[threadIdx.x] = v;
    __syncthreads();
#pragma unroll
    for (int off = 1; off < 512; off <<= 1) {
        int x = (threadIdx.x >= off) ? sh[threadIdx.x - off] : 0;
        __syncthreads();
        sh[threadIdx.x] += x;
        __syncthreads();
    }
    if (threadIdx.x < nb) bsum[threadIdx.x] = sh[threadIdx.x] - v;  // exclusive
}

__global__ void scan3_kernel(int* __restrict__ start, const int* __restrict__ bsum, int N) {
    int i = blockIdx.x * 256 + threadIdx.x;
    if (i < N) start[i] += bsum[blockIdx.x];
}

__global__ void scatter_kernel(const int* __restrict__ pidx,
                               const int* __restrict__ start,
                               int* __restrict__ cursor,
                               int* __restrict__ csr, int P) {
    int p = blockIdx.x * blockDim.x + threadIdx.x;
    if (p >= P) return;
    int hd = pidx[p];
    int pos = atomicAdd(cursor + hd, 1);
    csr[start[hd] + pos] = p;
}

// ---------------------------------------------------------------- layer1 attention, CSR, single pass.
// One wave per node. Softmax shift = upper bound leaky(dh + gm[h] + gt[h])
// (monotone leaky => bounds every path logit; softmax invariant to shift).
// Pre-phase: lane (h=lane>>3, k8=lane&7) computes ex for path k0+k8, head h
// (64 parallel gathers). Agg: shfl ex/tl within the 8-lane h-group, gather
// h1 rows (256B contiguous per path).
__global__ __launch_bounds__(256) void attn1_csr_kernel(
    const int* __restrict__ csr, const int* __restrict__ start,
    const int* __restrict__ deg, const int* __restrict__ pidx,
    const float* __restrict__ d1, const __hip_bfloat16* __restrict__ h1,
    const float* __restrict__ b1, const unsigned int* __restrict__ gmax,
    float* __restrict__ elu_out, int N, int P)
{
    int node = blockIdx.x * 4 + (threadIdx.x >> 6);
    if (node >= N) return;
    int lane = threadIdx.x & 63;
    int h = lane >> 3;
    int s0 = start[node], dg = deg[node];
    const float* d1m = d1 + (size_t)N * NHEAD;
    const float* d1t = d1 + (size_t)2 * N * NHEAD;
    const float dh = d1[node * NHEAD + h];
    float zub = dh + dec_f32(gmax[h]) + dec_f32(gmax[8 + h]);
    const float mxub = zub > 0.f ? zub : 0.2f * zub;

    float acc0 = 0.f, acc1 = 0.f, den = 0.f;
    for (int k0 = 0; k0 < dg; k0 += 8) {
        int kk = k0 + (lane & 7);
        bool valid = kk < dg;
        int p = csr[s0 + (valid ? kk : dg - 1)];
        int mid = pidx[P + p], tl = pidx[2 * P + p];
        float z = dh + d1m[mid * NHEAD + h] + d1t[tl * NHEAD + h];
        float e = z > 0.f ? z : 0.2f * z;
        float ex = valid ? __expf(e - mxub) : 0.f;
        den += ex;
        int kmax = dg - k0; if (kmax > 8) kmax = 8;
        for (int dk = 0; dk < kmax; dk++) {
            int tl_b = __shfl(tl, dk, 8);
            float ex_b = __shfl(ex, dk, 8);
            __hip_bfloat162 v = *(const __hip_bfloat162*)(h1 + (size_t)tl_b * HC + 2 * lane);
            acc0 += ex_b * bf(v.x);
            acc1 += ex_b * bf(v.y);
        }
    }
#pragma unroll
    for (int w = 1; w < 8; w <<= 1) den += __shfl_xor(den, w, 8);

    float inv = 1.f / (den + 1e-16f);
    int j0 = 2 * lane;
    float v0 = acc0 * inv + b1[j0];
    float v1 = acc1 * inv + b1[j0 + 1];
    v0 = v0 > 0.f ? v0 : __expf(v0) - 1.f;
    v1 = v1 > 0.f ? v1 : __expf(v1) - 1.f;
    *(float2*)(elu_out + (size_t)node * HC + j0) = make_float2(v0, v1);
}

// ---------------------------------------------------------------- layer2 GEMM + dots: h2 = elu @ W2 ; d2[j,n] = h2[n,:]·a2[j]
__global__ __launch_bounds__(256) void layer2_kernel(
    const float* __restrict__ elu, const float* __restrict__ W2,
    const float* __restrict__ a2,
    float* __restrict__ h2, float* __restrict__ d2, int N)
{
    __shared__ float rows[16][HC + 1];
    __shared__ float h2s[16][NCLS + 1];
    const int n0 = blockIdx.x * 16;
    const int tid = threadIdx.x;
    for (int idx = tid; idx < 16 * HC; idx += 256) {
        int r = idx >> 7, c = idx & 127;
        rows[r][c] = (n0 + r < N) ? elu[(size_t)(n0 + r) * HC + c] : 0.f;
    }
    __syncthreads();
    int ln = tid >> 4, c = tid & 15;
    float acc = 0.f;
#pragma unroll 8
    for (int j = 0; j < HC; j++) acc += rows[ln][j] * W2[j * NCLS + c];
    h2s[ln][c] = acc;
    if (n0 + ln < N) h2[(size_t)(n0 + ln) * NCLS + c] = acc;
    __syncthreads();
    if (tid < 48) {
        int l = tid / 3, j = tid - l * 3;
        if (n0 + l < N) {
            float s = 0.f;
#pragma unroll
            for (int cc = 0; cc < NCLS; cc++) s += h2s[l][cc] * a2[j * NCLS + cc];
            d2[j * N + n0 + l] = s;
        }
    }
}

// ---------------------------------------------------------------- layer2 attention CSR, single pass + log_softmax -> out (fp32)
__global__ __launch_bounds__(256) void attn2_csr_kernel(
    const int* __restrict__ csr, const int* __restrict__ start,
    const int* __restrict__ deg, const int* __restrict__ pidx,
    const float* __restrict__ d2, const float* __restrict__ h2,
    const float* __restrict__ b2, const unsigned int* __restrict__ gmax2,
    float* __restrict__ out, int N, int P)
{
    int node = blockIdx.x * 16 + (threadIdx.x >> 4);
    if (node >= N) return;
    int c = threadIdx.x & 15;
    int s0 = start[node], dg = deg[node];
    const float dh = d2[node];
    const float* d2m = d2 + N;
    const float* d2t = d2 + 2 * N;
    float zub = dh + dec_f32(gmax2[0]) + dec_f32(gmax2[1]);
    const float mxub = zub > 0.f ? zub : 0.2f * zub;

    float acc = 0.f, den = 0.f;
    for (int k0 = 0; k0 < dg; k0 += 16) {
        int kk = k0 + c;
        bool valid = kk < dg;
        int p = csr[s0 + (valid ? kk : dg - 1)];
        int mid = pidx[P + p], tl = pidx[2 * P + p];
        float z = dh + d2m[mid] + d2t[tl];
        float e = z > 0.f ? z : 0.2f * z;
        float ex = valid ? __expf(e - mxub) : 0.f;
        den += ex;
        int kmax = dg - k0; if (kmax > 16) kmax = 16;
        for (int dk = 0; dk < kmax; dk++) {
            int tl_b = __shfl(tl, dk, 16);
            float ex_b = __shfl(ex, dk, 16);
            acc += ex_b * h2[(size_t)tl_b * NCLS + c];
        }
    }
#pragma unroll
    for (int w = 1; w < 16; w <<= 1) den += __shfl_xor(den, w, 16);

    float o = acc / (den + 1e-16f) + b2[c];
    // log_softmax across the 16 lanes of this node
    float m2 = o;
#pragma unroll
    for (int w = 1; w < 16; w <<= 1) m2 = fmaxf(m2, __shfl_xor(m2, w, 16));
    float ex = __expf(o - m2), sm = ex;
#pragma unroll
    for (int w = 1; w < 16; w <<= 1) sm += __shfl_xor(sm, w, 16);
    float r = o - m2 - __logf(sm);
    out[(size_t)node * NCLS + c] = r;
}

// ================================================================ launch
extern "C" void kernel_launch(void* const* d_in, const int* in_sizes, int n_in,
                              void* d_out, int out_size, void* d_ws, size_t ws_size,
                              hipStream_t stream)
{
    const float* x  = (const float*)d_in[0];
    const int*   pi = (const int*)d_in[1];
    const float* W1 = (const float*)d_in[2];
    const float* a1 = (const float*)d_in[3];
    const float* b1 = (const float*)d_in[4];
    const float* W2 = (const float*)d_in[5];
    const float* a2 = (const float*)d_in[6];
    const float* b2 = (const float*)d_in[7];

    const int N = in_sizes[0] / F_IN;   // 100000
    const int P = in_sizes[1] / 3;      // 1000000

    float* ws = (float*)d_ws;
    // workspace (float units): peak ~238N + P + 67k floats (~99.5 MB)
    size_t off_h1     = 0;                          // 64N  (bf16 x 128N)
    size_t off_d1     = (size_t)64 * N;             // 24N
    size_t off_elu    = (size_t)88 * N;             // 128N
    size_t off_h2     = (size_t)216 * N;            // 16N
    size_t off_d2     = (size_t)232 * N;            // 3N
    size_t off_deg    = (size_t)235 * N;            // N (int)
    size_t off_start  = (size_t)236 * N;            // N (int)
    size_t off_cursor = (size_t)237 * N;            // N (int)
    size_t off_gmax   = (size_t)238 * N;            // 32 (uint: 16 for d1, 2 for d2)
    size_t off_bsum   = (size_t)238 * N + 32;       // 1024 (int)
    size_t off_csr    = (size_t)238 * N + 32 + 1024; // P (int)
    size_t off_w1th   = off_csr + P;                // 32768 (bf16 x 65536)
    size_t off_w1tl   = off_w1th + 32768;           // 32768

    __hip_bfloat16* h1 = (__hip_bfloat16*)(ws + off_h1);
    float* d1   = ws + off_d1;
    float* elu  = ws + off_elu;
    float* h2   = ws + off_h2;
    float* d2   = ws + off_d2;
    int* deg    = (int*)(ws + off_deg);
    int* start  = (int*)(ws + off_start);
    int* cursor = (int*)(ws + off_cursor);
    unsigned int* gmax  = (unsigned int*)(ws + off_gmax);       // 16
    unsigned int* gmax2 = (unsigned int*)(ws + off_gmax) + 16;  // 2
    int* bsum   = (int*)(ws + off_bsum);
    int* csr    = (int*)(ws + off_csr);
    __bf16* w1t_hi = (__bf16*)(ws + off_w1th);
    __bf16* w1t_lo = (__bf16*)(ws + off_w1tl);

    const int BLK = 256;
    const int nb = (N + 255) / 256;   // scan blocks (<= 512)

    transpose_w1<<<(HC * KPAD) / 256, 256, 0, stream>>>(W1, w1t_hi, w1t_lo);
    // zero deg, start, cursor, gmax (3N + 32 ints contiguous)
    zero_i32<<<(3 * N + 32 + BLK - 1) / BLK, BLK, 0, stream>>>(deg, 3 * N + 32);
    gemm1_mfma<<<(N + 127) / 128, 256, 0, stream>>>(x, w1t_hi, w1t_lo, h1, N);
    dots1_kernel<<<(N * NHEAD + BLK - 1) / BLK, BLK, 0, stream>>>(h1, a1, d1, N);
    maxred_d1<<<1024, 256, 0, stream>>>(d1, gmax, N);
    // CSR build
    hist_kernel<<<(P + BLK - 1) / BLK, BLK, 0, stream>>>(pi, deg, P);
    scan1_kernel<<<nb, 256, 0, stream>>>(deg, start, bsum, N);
    scan2_kernel<<<1, 512, 0, stream>>>(bsum, nb);
    scan3_kernel<<<nb, 256, 0, stream>>>(start, bsum, N);
    scatter_kernel<<<(P + BLK - 1) / BLK, BLK, 0, stream>>>(pi, start, cursor, csr, P);
    // layer 1 attention (single-pass, fused softmax/aggregate/bias/elu)
    attn1_csr_kernel<<<(N + 3) / 4, 256, 0, stream>>>(csr, start, deg, pi, d1, h1, b1, gmax, elu, N, P);
    // layer 2
    layer2_kernel<<<(N + 15) / 16, 256, 0, stream>>>(elu, W2, a2, h2, d2, N);
    maxred_d2<<<256, 256, 0, stream>>>(d2, gmax2, N);
    attn2_csr_kernel<<<(N + 15) / 16, 256, 0, stream>>>(csr, start, deg, pi, d2, h2, b2, gmax2,
                                                        (float*)d_out, N, P);
}